// Round 14
// baseline (165.443 us; speedup 1.0000x reference)
//
#include <hip/hip_runtime.h>
#include <stdint.h>

// CtxAttention: additive attention (Bahdanau).
//   e[n,t]  = sum_a w_v[a] * tanh( enc_pad[n,t,:]·W_enc[a,:] + b_enc[a] + dec_prev[n,:]·W_dec[a,:] )
//   ali     = softmax_t(mask(e));  ctx[n,:] = sum_t ali[n,t] * enc_pad[n,t,:]
// Round-14: the 13-round invariant is ACCESS CONTIGUITY on enc: strided 32-256B
// segment readers all run 1.5-2.3 TB/s (convert x6, fused-A GEMMs x4 ~86us); contiguous
// readers run 5-7 TB/s (ctxpart, fill, fp16-tile score). k_score256 now stages A in
// CONTIGUOUS 1KB full-row wave-ops: BM=64, K in 2 halves (64 rows x 1KB fp32 = 64KB),
// GLD16 w/ swizzle baked into per-lane src; A dbuf across halves (chunked issue,
// counted vmcnt(1)); B = R9 k-major panels, single 32KB buffer. LDS 160KB exactly.

#define NB  32
#define TI  2000
#define ED  512
#define AD  512
#define M_TOT (NB * TI)          // 64000
#define NSPLIT 20
#define TCHUNK (TI / NSPLIT)     // 100
#define MTS 1000                 // 64-row m-tiles
#define NKS 16                   // K-steps of 32

using f16x8 = __attribute__((ext_vector_type(8))) _Float16;
using f32x4 = __attribute__((ext_vector_type(4))) float;

#define GLD16(g, l)                                                     \
    __builtin_amdgcn_global_load_lds(                                   \
        (const __attribute__((address_space(1))) void*)(g),             \
        (__attribute__((address_space(3))) void*)(l), 16, 0, 0)

__device__ __forceinline__ float fast_tanh(float s) {
    s = fminf(fmaxf(s, -15.f), 15.f);
    float t = __expf(2.f * s);
    return __fdividef(t - 1.f, t + 1.f);
}

__device__ __forceinline__ f16x8 cvt8(float4 a, float4 b) {
    f16x8 h;
    h[0] = (_Float16)a.x; h[1] = (_Float16)a.y; h[2] = (_Float16)a.z; h[3] = (_Float16)a.w;
    h[4] = (_Float16)b.x; h[5] = (_Float16)b.y; h[6] = (_Float16)b.z; h[7] = (_Float16)b.w;
    return h;
}

// ---------------- Kernel 0: W_enc -> W16 (512 KB, k-major panels); + fused decdb ----------
// W16: 16 slabs (ks) of 32 KB; slab = 4 panels (gk) of 8 KB; panel: a (0..511) x 16 B
// holding f16 W_enc[a][ks*32+gk*8 .. +8].
// bx in [0,128): convert; [128,160): decdb row n = bx-128.
__global__ void k_wconvert(const float* __restrict__ Wenc, _Float16* __restrict__ W16,
                           const float* __restrict__ dec_prev, const float* __restrict__ W_dec,
                           const float* __restrict__ b_enc, float* __restrict__ db) {
    __shared__ float xd[ED];
    int bx = blockIdx.x;
    int tid = threadIdx.x;
    if (bx >= 128) {
        int n = bx - 128;
        for (int k = tid; k < ED; k += 256) xd[k] = dec_prev[n * ED + k];
        __syncthreads();
        for (int a = tid; a < AD; a += 256) {
            const float* wr = W_dec + (size_t)a * ED;
            float s = 0.f;
#pragma unroll 8
            for (int k = 0; k < ED; k += 4) {
                float4 w = *(const float4*)(wr + k);
                s += xd[k] * w.x + xd[k + 1] * w.y + xd[k + 2] * w.z + xd[k + 3] * w.w;
            }
            db[n * AD + a] = s + b_enc[a];
        }
        return;
    }
    int idx = bx * 4096 + tid * 16;    // physical byte in W16 (512 KB)
    int ks  = idx >> 15;               // slab 0..15
    int r   = idx & 32767;
    int gk  = r >> 13;                 // panel 0..3
    int a   = (r & 8191) >> 4;         // row 0..511
    int k   = ks * 32 + gk * 8;
    const float* s = Wenc + (size_t)a * ED + k;
    float4 x0 = *(const float4*)s;
    float4 x1 = *(const float4*)(s + 4);
    *(f16x8*)((char*)W16 + idx) = cvt8(x0, x1);
}

// ---------------- standalone decdb (fallback path only) ----------------
__global__ void k_decdb(const float* __restrict__ dec_prev,
                        const float* __restrict__ W_dec,
                        const float* __restrict__ b_enc,
                        float* __restrict__ db) {
    int n = blockIdx.x;
    __shared__ float xd[ED];
    for (int k = threadIdx.x; k < ED; k += 256) xd[k] = dec_prev[n * ED + k];
    __syncthreads();
    for (int a = threadIdx.x; a < AD; a += 256) {
        const float* wr = W_dec + (size_t)a * ED;
        float s = 0.f;
#pragma unroll 8
        for (int k = 0; k < ED; k += 4) {
            float4 w = *(const float4*)(wr + k);
            s += xd[k] * w.x + xd[k + 1] * w.y + xd[k + 2] * w.z + xd[k + 3] * w.w;
        }
        db[n * AD + a] = s + b_enc[a];
    }
}

// ---------------- Kernel 2: fused score GEMM, 64x512 tile, contiguous-row A staging --------
__launch_bounds__(512, 1)
__global__ void k_score256(const float* __restrict__ enc, const _Float16* __restrict__ W16,
                           const float* __restrict__ db, const float* __restrict__ wv,
                           float* __restrict__ e_out) {
    __shared__ alignas(16) char As0[65536];   // 64 rows x 256 fp32 (K-half 0), XOR-swizzled
    __shared__ alignas(16) char As1[65536];   // K-half 1
    __shared__ alignas(16) char Bs[32768];    // 4 k-panels x (512 x 16B f16), single buffer

    const int mt   = blockIdx.x;
    const int tid  = threadIdx.x;
    const int lane = tid & 63;
    const int w    = tid >> 6;        // wave 0..7
    const int wn   = w;               // N-eighth: cols wn*64..+64
    const int m0   = mt * 64;
    const int lr   = lane & 15;
    const int gk   = lane >> 4;       // k-group 0..3

    // A chunk c stages rows [8c, 8c+8): one wave-op = one CONTIGUOUS 1KB enc row
    // (swizzle applied to the per-lane source offset; LDS dest linear).
    const int arow_base = tid >> 6;                 // wave index = row within chunk... row = c*8 + (tid>>6)
    const int awithin   = (tid & 63) * 16;          // byte within 1KB row

    const char* wbase = (const char*)W16;

    f32x4 acc[4][4];
#pragma unroll
    for (int rb = 0; rb < 4; ++rb)
#pragma unroll
        for (int cb = 0; cb < 4; ++cb) acc[rb][cb] = (f32x4){0.f, 0.f, 0.f, 0.f};

#define STAGE_A(c, half, dst)                                              \
    {                                                                      \
        int row_ = (c) * 8 + arow_base;                                    \
        int g_   = (awithin ^ ((row_ & 7) << 4)) >> 2;                     \
        const float* gp_ = enc + (size_t)(m0 + row_) * ED + (half) * 256 + g_; \
        GLD16(gp_, (dst) + (c) * 8192 + tid * 16);                         \
    }

#define STAGE_B(ks)                                                     \
    {                                                                   \
        const char* wsl = wbase + ((ks) << 15);                         \
        GLD16(wsl + tid * 16,          Bs + tid * 16);                  \
        GLD16(wsl + 8192 + tid * 16,   Bs + 8192 + tid * 16);           \
        GLD16(wsl + 16384 + tid * 16,  Bs + 16384 + tid * 16);          \
        GLD16(wsl + 24576 + tid * 16,  Bs + 24576 + tid * 16);          \
    }

#define COMPUTE(ksl, sA)                                                         \
    {                                                                            \
        f16x8 aF[4], bF[4];                                                      \
        _Pragma("unroll")                                                        \
        for (int rb = 0; rb < 4; ++rb) {                                         \
            int row = rb * 16 + lr;                                              \
            int b0  = row * 1024 + (ksl) * 128 + gk * 32;                        \
            int sw  = (row & 7) << 4;                                            \
            f32x4 lo = *(const f32x4*)((sA) + (b0 ^ sw));                        \
            f32x4 hi = *(const f32x4*)((sA) + ((b0 + 16) ^ sw));                 \
            f16x8 h;                                                             \
            h[0] = (_Float16)lo[0]; h[1] = (_Float16)lo[1];                      \
            h[2] = (_Float16)lo[2]; h[3] = (_Float16)lo[3];                      \
            h[4] = (_Float16)hi[0]; h[5] = (_Float16)hi[1];                      \
            h[6] = (_Float16)hi[2]; h[7] = (_Float16)hi[3];                      \
            aF[rb] = h;                                                          \
        }                                                                        \
        _Pragma("unroll")                                                        \
        for (int cb = 0; cb < 4; ++cb) {                                         \
            int brow = wn * 64 + cb * 16 + lr;                                   \
            bF[cb] = *(const f16x8*)(Bs + gk * 8192 + brow * 16);                \
        }                                                                        \
        __builtin_amdgcn_s_setprio(1);                                           \
        _Pragma("unroll")                                                        \
        for (int rb = 0; rb < 4; ++rb)                                           \
            _Pragma("unroll")                                                    \
            for (int cb = 0; cb < 4; ++cb)                                       \
                acc[rb][cb] = __builtin_amdgcn_mfma_f32_16x16x32_f16(            \
                    aF[rb], bF[cb], acc[rb][cb], 0, 0, 0);                       \
        __builtin_amdgcn_s_setprio(0);                                           \
    }

#define WAITV0 { asm volatile("s_waitcnt vmcnt(0)" ::: "memory"); __builtin_amdgcn_sched_barrier(0); }
#define WAITV1 { asm volatile("s_waitcnt vmcnt(1)" ::: "memory"); __builtin_amdgcn_sched_barrier(0); }
#define BAR __builtin_amdgcn_s_barrier()

    // prologue: A half-0 (8 chunks, contiguous rows) + B slab 0
#pragma unroll
    for (int c = 0; c < 8; ++c) STAGE_A(c, 0, As0);
    STAGE_B(0);
    WAITV0; BAR;

    // steps 0..6: compute(As0,k) | stage B(k+1) + one A1 chunk; vmcnt(1) keeps the
    // newest A chunk in flight while guaranteeing B(k+1) landed (issue order: B then A).
#pragma unroll
    for (int k = 0; k < 7; ++k) {
        COMPUTE(k, As0);
        BAR;
        STAGE_B(k + 1);
        STAGE_A(k, 1, As1);
        WAITV1; BAR;
    }
    // step 7: last A1 chunk; drain everything (As1 fully needed next step)
    COMPUTE(7, As0);
    BAR;
    STAGE_B(8);
    STAGE_A(7, 1, As1);
    WAITV0; BAR;
    // steps 8..14
#pragma unroll
    for (int k = 8; k < 15; ++k) {
        COMPUTE(k - 8, As1);
        BAR;
        STAGE_B(k + 1);
        WAITV0; BAR;
    }
    COMPUTE(7, As1);
    __syncthreads();
#undef WAITV0
#undef WAITV1
#undef BAR
#undef COMPUTE
#undef STAGE_B
#undef STAGE_A

    // epilogue: rs = sum over this wave's 64 cols of w_v*tanh(acc+db); shfl-reduce the
    // 16 col-lanes; cross-wave (8 wn eighths) reduce via e_red overlaid on As0.
    float* e_red = (float*)As0;   // [8][64] = 2 KB
    float wvv[4];
#pragma unroll
    for (int cb = 0; cb < 4; ++cb) wvv[cb] = wv[wn * 64 + cb * 16 + lr];

#pragma unroll
    for (int rb = 0; rb < 4; ++rb) {
#pragma unroll
        for (int i = 0; i < 4; ++i) {
            int row_local = rb * 16 + gk * 4 + i;   // C/D: row=(lane>>4)*4+reg
            int m = m0 + row_local;
            int n = m / TI;
            const float* dbp = db + (size_t)n * AD + wn * 64;
            float rs = 0.f;
#pragma unroll
            for (int cb = 0; cb < 4; ++cb) {
                float s = acc[rb][cb][i] + dbp[cb * 16 + lr];  // col = lane&15
                rs += fast_tanh(s) * wvv[cb];
            }
            rs += __shfl_xor(rs, 1);
            rs += __shfl_xor(rs, 2);
            rs += __shfl_xor(rs, 4);
            rs += __shfl_xor(rs, 8);
            if (lr == 0) e_red[wn * 64 + row_local] = rs;
        }
    }
    __syncthreads();
    if (tid < 64) {
        float s = 0.f;
#pragma unroll
        for (int q = 0; q < 8; ++q) s += e_red[q * 64 + tid];
        e_out[m0 + tid] = s;
    }
}

// ---------------- fallback fp32 GEMM (convert-in-kernel) if ws too small ----------------
__launch_bounds__(256, 2)
__global__ void k_score_fb(const float* __restrict__ X, const float* __restrict__ W,
                           const float* __restrict__ db, const float* __restrict__ wv,
                           float* __restrict__ e_part) {
    __shared__ alignas(16) _Float16 Xs[128][72];
    __shared__ alignas(16) _Float16 Ws[128][72];
    __shared__ float e_red[2][128];

    const int tid = threadIdx.x, lane = tid & 63, wid = tid >> 6;
    const int wr = wid >> 1, wc = wid & 1;
    const int m0 = blockIdx.x * 128, a0 = blockIdx.y * 128;

    f32x4 acc[4][4];
#pragma unroll
    for (int rb = 0; rb < 4; ++rb)
#pragma unroll
        for (int cb = 0; cb < 4; ++cb) acc[rb][cb] = (f32x4){0.f, 0.f, 0.f, 0.f};

    const int lr = lane & 15;
    const int lk = (lane >> 4) << 3;

    for (int kt = 0; kt < ED; kt += 64) {
#pragma unroll
        for (int i = 0; i < 4; ++i) {
            int idx = tid + i * 256, r = idx >> 3, c = (idx & 7) << 3;
            const float* gx = X + (size_t)(m0 + r) * ED + kt + c;
            float4 x0 = *(const float4*)gx, x1 = *(const float4*)(gx + 4);
            *(f16x8*)&Xs[r][c] = cvt8(x0, x1);
            const float* gw = W + (size_t)(a0 + r) * ED + kt + c;
            float4 w0 = *(const float4*)gw, w1 = *(const float4*)(gw + 4);
            *(f16x8*)&Ws[r][c] = cvt8(w0, w1);
        }
        __syncthreads();
#pragma unroll
        for (int kb = 0; kb < 64; kb += 32) {
            f16x8 aF[4], bF[4];
#pragma unroll
            for (int rb = 0; rb < 4; ++rb) aF[rb] = *(const f16x8*)&Xs[wr * 64 + rb * 16 + lr][kb + lk];
#pragma unroll
            for (int cb = 0; cb < 4; ++cb) bF[cb] = *(const f16x8*)&Ws[wc * 64 + cb * 16 + lr][kb + lk];
#pragma unroll
            for (int rb = 0; rb < 4; ++rb)
#pragma unroll
                for (int cb = 0; cb < 4; ++cb)
                    acc[rb][cb] = __builtin_amdgcn_mfma_f32_16x16x32_f16(aF[rb], bF[cb], acc[rb][cb], 0, 0, 0);
        }
        __syncthreads();
    }

    const int lg = lane >> 4;
    float wvv[4];
#pragma unroll
    for (int cb = 0; cb < 4; ++cb) wvv[cb] = wv[a0 + wc * 64 + cb * 16 + lr];
#pragma unroll
    for (int rb = 0; rb < 4; ++rb) {
#pragma unroll
        for (int i = 0; i < 4; ++i) {
            int row_local = wr * 64 + rb * 16 + lg * 4 + i;
            int m = m0 + row_local;
            int n = m / TI;
            const float* dbp = db + (size_t)n * AD + a0 + wc * 64;
            float rs = 0.f;
#pragma unroll
            for (int cb = 0; cb < 4; ++cb) {
                float s = acc[rb][cb][i] + dbp[cb * 16 + lr];
                rs += fast_tanh(s) * wvv[cb];
            }
            rs += __shfl_xor(rs, 1);
            rs += __shfl_xor(rs, 2);
            rs += __shfl_xor(rs, 4);
            rs += __shfl_xor(rs, 8);
            if (lr == 0) e_red[wc][row_local] = rs;
        }
    }
    __syncthreads();
    if (tid < 128)
        e_part[(size_t)blockIdx.y * M_TOT + m0 + tid] = e_red[0][tid] + e_red[1][tid];
}

// ---------------- Kernel 3: masked softmax over t, per n ----------------
__global__ void k_softmax(const float* __restrict__ e_part,
                          const int* __restrict__ enc_len,
                          float* __restrict__ ali, int nparts) {
    int n = blockIdx.x;
    int len = enc_len[n];
    __shared__ float se[TI];
    __shared__ float redm[4];
    __shared__ float reds[4];
    int tid = threadIdx.x;
    int lane = tid & 63, wid = tid >> 6;

    for (int t = tid; t < TI; t += 256) {
        float s = 0.f;
        for (int p = 0; p < nparts; ++p) s += e_part[(size_t)p * M_TOT + n * TI + t];
        se[t] = s;
    }
    __syncthreads();

    float mx = -1e30f;
    for (int t = tid; t < len; t += 256) mx = fmaxf(mx, se[t]);
#pragma unroll
    for (int o = 32; o >= 1; o >>= 1) mx = fmaxf(mx, __shfl_xor(mx, o));
    if (lane == 0) redm[wid] = mx;
    __syncthreads();
    mx = fmaxf(fmaxf(redm[0], redm[1]), fmaxf(redm[2], redm[3]));

    float sm = 0.f;
    for (int t = tid; t < len; t += 256) {
        float ex = __expf(se[t] - mx);
        se[t] = ex;
        sm += ex;
    }
#pragma unroll
    for (int o = 32; o >= 1; o >>= 1) sm += __shfl_xor(sm, o);
    if (lane == 0) reds[wid] = sm;
    __syncthreads();
    float inv = 1.f / (reds[0] + reds[1] + reds[2] + reds[3]);

    for (int t = tid; t < TI; t += 256)
        ali[n * TI + t] = (t < len) ? se[t] * inv : 0.f;
}

// ---------------- Kernel 4: ctx partials over t-chunks (fp32 enc, L3-warm) ----------------
__global__ void k_ctxpart(const float* __restrict__ enc,
                          const float* __restrict__ ali,
                          float* __restrict__ cpart) {
    int s = blockIdx.x;   // 0..NSPLIT-1
    int n = blockIdx.y;   // 0..31
    int d0 = threadIdx.x * 2;
    const float* base = enc + ((size_t)n * TI + s * TCHUNK) * ED + d0;
    const float* ap = ali + n * TI + s * TCHUNK;
    float ax = 0.f, ay = 0.f;
#pragma unroll 4
    for (int t = 0; t < TCHUNK; ++t) {
        float a = ap[t];
        float2 v = *(const float2*)(base + (size_t)t * ED);
        ax = fmaf(a, v.x, ax);
        ay = fmaf(a, v.y, ay);
    }
    float2 r; r.x = ax; r.y = ay;
    *(float2*)&cpart[((size_t)(n * NSPLIT + s)) * ED + d0] = r;
}

// ---------------- Kernel 5: reduce ctx partials ----------------
__global__ void k_ctxred(const float* __restrict__ cpart, float* __restrict__ ctx) {
    int n = blockIdx.x;
    for (int d = threadIdx.x; d < ED; d += 256) {
        float sum = 0.f;
#pragma unroll
        for (int s = 0; s < NSPLIT; ++s) sum += cpart[((size_t)(n * NSPLIT + s)) * ED + d];
        ctx[(size_t)n * ED + d] = sum;
    }
}

extern "C" void kernel_launch(void* const* d_in, const int* in_sizes, int n_in,
                              void* d_out, int out_size, void* d_ws, size_t ws_size,
                              hipStream_t stream) {
    const float* enc_pad  = (const float*)d_in[0];
    const int*   enc_len  = (const int*)d_in[1];
    const float* dec_prev = (const float*)d_in[2];
    // d_in[3] = ali_prev (unused by reference)
    const float* W_enc    = (const float*)d_in[4];
    const float* b_enc    = (const float*)d_in[5];
    const float* W_dec    = (const float*)d_in[6];
    const float* w_v      = (const float*)d_in[7];

    float* out = (float*)d_out;
    float* ali = out;              // 64000 floats
    float* ctx = out + M_TOT;      // 16384 floats

    float* ws     = (float*)d_ws;
    float* db     = ws;                          // 32*512
    float* e_part = ws + NB * AD;                // up to 4*64000 (main path uses 1)
    float* cpart  = e_part + 4 * M_TOT;          // 32*20*512
    size_t fp_floats = (size_t)NB * AD + 4 * M_TOT + (size_t)NB * NSPLIT * ED;  // 600064
    _Float16* W16 = (_Float16*)((char*)d_ws + fp_floats * 4);
    size_t need = fp_floats * 4 + (size_t)512 * 1024;   // ~2.9 MB
    bool big = ws_size >= need;

    if (big) {
        hipLaunchKernelGGL(k_wconvert, dim3(160), dim3(256), 0, stream,
                           W_enc, W16, dec_prev, W_dec, b_enc, db);
        hipLaunchKernelGGL(k_score256, dim3(MTS), dim3(512), 0, stream,
                           enc_pad, W16, db, w_v, e_part);
        hipLaunchKernelGGL(k_softmax, dim3(NB), dim3(256), 0, stream, e_part, enc_len, ali, 1);
    } else {
        hipLaunchKernelGGL(k_decdb, dim3(NB), dim3(256), 0, stream, dec_prev, W_dec, b_enc, db);
        hipLaunchKernelGGL(k_score_fb, dim3(M_TOT / 128, 4), dim3(256), 0, stream,
                           enc_pad, W_enc, db, w_v, e_part);
        hipLaunchKernelGGL(k_softmax, dim3(NB), dim3(256), 0, stream, e_part, enc_len, ali, 4);
    }
    hipLaunchKernelGGL(k_ctxpart, dim3(NSPLIT, NB), dim3(256), 0, stream, enc_pad, ali, cpart);
    hipLaunchKernelGGL(k_ctxred, dim3(NB), dim3(256), 0, stream, cpart, ctx);
}

// Round 15
// 132.466 us; speedup vs baseline: 1.2489x; 1.2489x over previous
//
#include <hip/hip_runtime.h>
#include <stdint.h>

// CtxAttention: additive attention (Bahdanau).
//   e[n,t]  = sum_a w_v[a] * tanh( enc_pad[n,t,:]·W_enc[a,:] + b_enc[a] + dec_prev[n,:]·W_dec[a,:] )
//   ali     = softmax_t(mask(e));  ctx[n,:] = sum_t ali[n,t] * enc_pad[n,t,:]
// Round-15: test CROSS-BLOCK overlap. Every fused score so far ran 1 block/CU
// (LDS>=96KB) -> all waves share one barrier -> CU idles at every vmcnt drain
// (R13: more waves in ONE block = null). Now BM=128 x BN=256, BK=32 dbuf,
// LDS=64KB -> 2 independent blocks/CU can slip past each other's barriers (m114).
// A: R13's verified fp32 GLD16 (XOR-src) + cvt-on-read. B: per-at2 k-major panels,
// conflict-free. Grid 1000, at2-pairs XCD-grouped. R14's contiguity theory dead
// (m97 ran same strided pattern fast; R14 also self-inflicted 1KB-stride conflicts).

#define NB  32
#define TI  2000
#define ED  512
#define AD  512
#define M_TOT (NB * TI)          // 64000
#define NSPLIT 20
#define TCHUNK (TI / NSPLIT)     // 100
#define MTS 500                  // 128-row m-tiles
#define NKS 16                   // K-steps of 32

using f16x8 = __attribute__((ext_vector_type(8))) _Float16;
using f32x4 = __attribute__((ext_vector_type(4))) float;

#define GLD16(g, l)                                                     \
    __builtin_amdgcn_global_load_lds(                                   \
        (const __attribute__((address_space(1))) void*)(g),             \
        (__attribute__((address_space(3))) void*)(l), 16, 0, 0)

__device__ __forceinline__ float fast_tanh(float s) {
    s = fminf(fmaxf(s, -15.f), 15.f);
    float t = __expf(2.f * s);
    return __fdividef(t - 1.f, t + 1.f);
}

__device__ __forceinline__ f16x8 cvt8(float4 a, float4 b) {
    f16x8 h;
    h[0] = (_Float16)a.x; h[1] = (_Float16)a.y; h[2] = (_Float16)a.z; h[3] = (_Float16)a.w;
    h[4] = (_Float16)b.x; h[5] = (_Float16)b.y; h[6] = (_Float16)b.z; h[7] = (_Float16)b.w;
    return h;
}

// ---------------- Kernel 0: W_enc -> W16 (512 KB, k-major panels); + fused decdb ----------
// W16: 16 slabs (ks) of 32 KB; slab = 4 panels (gk) of 8 KB; panel: a (0..511) x 16 B
// holding f16 W_enc[a][ks*32+gk*8 .. +8].
// bx in [0,128): convert; [128,160): decdb row n = bx-128.
__global__ void k_wconvert(const float* __restrict__ Wenc, _Float16* __restrict__ W16,
                           const float* __restrict__ dec_prev, const float* __restrict__ W_dec,
                           const float* __restrict__ b_enc, float* __restrict__ db) {
    __shared__ float xd[ED];
    int bx = blockIdx.x;
    int tid = threadIdx.x;
    if (bx >= 128) {
        int n = bx - 128;
        for (int k = tid; k < ED; k += 256) xd[k] = dec_prev[n * ED + k];
        __syncthreads();
        for (int a = tid; a < AD; a += 256) {
            const float* wr = W_dec + (size_t)a * ED;
            float s = 0.f;
#pragma unroll 8
            for (int k = 0; k < ED; k += 4) {
                float4 w = *(const float4*)(wr + k);
                s += xd[k] * w.x + xd[k + 1] * w.y + xd[k + 2] * w.z + xd[k + 3] * w.w;
            }
            db[n * AD + a] = s + b_enc[a];
        }
        return;
    }
    int idx = bx * 4096 + tid * 16;    // physical byte in W16 (512 KB)
    int ks  = idx >> 15;               // slab 0..15
    int r   = idx & 32767;
    int gk  = r >> 13;                 // panel 0..3
    int a   = (r & 8191) >> 4;         // row 0..511
    int k   = ks * 32 + gk * 8;
    const float* s = Wenc + (size_t)a * ED + k;
    float4 x0 = *(const float4*)s;
    float4 x1 = *(const float4*)(s + 4);
    *(f16x8*)((char*)W16 + idx) = cvt8(x0, x1);
}

// ---------------- standalone decdb (fallback path only) ----------------
__global__ void k_decdb(const float* __restrict__ dec_prev,
                        const float* __restrict__ W_dec,
                        const float* __restrict__ b_enc,
                        float* __restrict__ db) {
    int n = blockIdx.x;
    __shared__ float xd[ED];
    for (int k = threadIdx.x; k < ED; k += 256) xd[k] = dec_prev[n * ED + k];
    __syncthreads();
    for (int a = threadIdx.x; a < AD; a += 256) {
        const float* wr = W_dec + (size_t)a * ED;
        float s = 0.f;
#pragma unroll 8
        for (int k = 0; k < ED; k += 4) {
            float4 w = *(const float4*)(wr + k);
            s += xd[k] * w.x + xd[k + 1] * w.y + xd[k + 2] * w.z + xd[k + 3] * w.w;
        }
        db[n * AD + a] = s + b_enc[a];
    }
}

// ---------------- Kernel 2: fused score GEMM, 128x256 tile, 8 waves, 64KB LDS ----------
// grid 1008: fid -> g=fid>>4, r=fid&15, at2=r>>3, mt=g*8+(r&7) -> the two at2 blocks
// of one mt are 8 apart in fid (same XCD under round-robin) for enc L2 reuse.
__launch_bounds__(512, 2)
__global__ void k_score256(const float* __restrict__ enc, const _Float16* __restrict__ W16,
                           const float* __restrict__ db, const float* __restrict__ wv,
                           float* __restrict__ e_part) {
    __shared__ alignas(16) char As0[16384];   // 128 x 32 fp32, 128B rows, XOR-swizzled
    __shared__ alignas(16) char As1[16384];
    __shared__ alignas(16) char Bs0[16384];   // 4 k-panels x (256 x 16B f16), linear
    __shared__ alignas(16) char Bs1[16384];

    int fid = blockIdx.x;
    int g = fid >> 4, r = fid & 15;
    int at2 = r >> 3;
    int mt  = g * 8 + (r & 7);
    if (mt >= MTS) return;

    const int tid  = threadIdx.x;
    const int lane = tid & 63;
    const int w    = tid >> 6;        // wave 0..7
    const int wm   = w >> 2;          // M-half: rows wm*64..+64
    const int wn   = w & 3;           // N-quarter: cols wn*64..+64
    const int m0   = mt * 128;
    const int a0   = at2 * 256;
    const int lr   = lane & 15;
    const int gk   = lane >> 4;       // k-group 0..3

    // A staging: 2 GLD16/thread. LDS bytes d and d+8192; row(d)=d>>7 (0..127),
    // within-row swizzled source (inverse of read-side XOR). row(d+8192)=row(d)+64
    // has the same (row&7) -> same swizzle offset.
    const int da   = tid * 16;                          // 0..8176
    const int arow = da >> 7;                           // 0..63
    const int aswz = ((da & 127) ^ ((arow & 7) << 4)) >> 2;
    const float* asrc = enc + (size_t)(m0 + arow) * ED + aswz;

    // B staging: 2 GLD16/thread. Dest byte d: gk=d>>12, r16=(d&4095)>>4 (0..255);
    // src = W16 + (ks<<15) + gk*8192 + at2*4096 + (d&4095).
    const char* wbase = (const char*)W16;
    const int db0 = tid * 16;           // dest 0..8176 (gk 0..1)
    const int db1 = db0 + 8192;         // dest (gk 2..3)
    const int bs0 = ((db0 >> 12) << 13) + at2 * 4096 + (db0 & 4095);
    const int bs1 = ((db1 >> 12) << 13) + at2 * 4096 + (db1 & 4095);

    f32x4 acc[4][4];
#pragma unroll
    for (int rb = 0; rb < 4; ++rb)
#pragma unroll
        for (int cb = 0; cb < 4; ++cb) acc[rb][cb] = (f32x4){0.f, 0.f, 0.f, 0.f};

#define STAGE(ks, dA, dB)                                               \
    {                                                                   \
        GLD16(asrc + (ks) * 32,            (dA) + da);                  \
        GLD16(asrc + 64 * ED + (ks) * 32,  (dA) + da + 8192);           \
        const char* wsl = wbase + ((ks) << 15);                         \
        GLD16(wsl + bs0, (dB) + db0);                                   \
        GLD16(wsl + bs1, (dB) + db1);                                   \
    }

#define COMPUTE(sA, sB)                                                          \
    {                                                                            \
        f16x8 aF[4], bF[4];                                                      \
        _Pragma("unroll")                                                        \
        for (int rb = 0; rb < 4; ++rb) {                                         \
            int row = wm * 64 + rb * 16 + lr;                                    \
            int b0  = row * 128 + gk * 32;                                       \
            int sw  = (row & 7) << 4;                                            \
            f32x4 lo = *(const f32x4*)((sA) + (b0 ^ sw));                        \
            f32x4 hi = *(const f32x4*)((sA) + ((b0 + 16) ^ sw));                 \
            f16x8 h;                                                             \
            h[0] = (_Float16)lo[0]; h[1] = (_Float16)lo[1];                      \
            h[2] = (_Float16)lo[2]; h[3] = (_Float16)lo[3];                      \
            h[4] = (_Float16)hi[0]; h[5] = (_Float16)hi[1];                      \
            h[6] = (_Float16)hi[2]; h[7] = (_Float16)hi[3];                      \
            aF[rb] = h;                                                          \
        }                                                                        \
        _Pragma("unroll")                                                        \
        for (int cb = 0; cb < 4; ++cb) {                                         \
            int brow = wn * 64 + cb * 16 + lr;                                   \
            bF[cb] = *(const f16x8*)((sB) + gk * 4096 + brow * 16);              \
        }                                                                        \
        __builtin_amdgcn_s_setprio(1);                                           \
        _Pragma("unroll")                                                        \
        for (int rb = 0; rb < 4; ++rb)                                           \
            _Pragma("unroll")                                                    \
            for (int cb = 0; cb < 4; ++cb)                                       \
                acc[rb][cb] = __builtin_amdgcn_mfma_f32_16x16x32_f16(            \
                    aF[rb], bF[cb], acc[rb][cb], 0, 0, 0);                       \
        __builtin_amdgcn_s_setprio(0);                                           \
    }

#define ITER(k, Ac, Bc, An, Bn)  STAGE(k + 1, An, Bn); COMPUTE(Ac, Bc); __syncthreads();

    STAGE(0, As0, Bs0); __syncthreads();
    ITER(0,  As0, Bs0, As1, Bs1)
    ITER(1,  As1, Bs1, As0, Bs0)
    ITER(2,  As0, Bs0, As1, Bs1)
    ITER(3,  As1, Bs1, As0, Bs0)
    ITER(4,  As0, Bs0, As1, Bs1)
    ITER(5,  As1, Bs1, As0, Bs0)
    ITER(6,  As0, Bs0, As1, Bs1)
    ITER(7,  As1, Bs1, As0, Bs0)
    ITER(8,  As0, Bs0, As1, Bs1)
    ITER(9,  As1, Bs1, As0, Bs0)
    ITER(10, As0, Bs0, As1, Bs1)
    ITER(11, As1, Bs1, As0, Bs0)
    ITER(12, As0, Bs0, As1, Bs1)
    ITER(13, As1, Bs1, As0, Bs0)
    ITER(14, As0, Bs0, As1, Bs1)
    COMPUTE(As1, Bs1); __syncthreads();
#undef ITER
#undef COMPUTE
#undef STAGE

    // epilogue: rs = sum over this wave's 64 cols of w_v*tanh(acc+db); shfl-reduce the
    // 16 col-lanes; cross-wave (4 wn quarters) reduce via e_red overlaid on As0.
    float* e_red = (float*)As0;   // [4][128] = 2 KB
    float wvv[4];
#pragma unroll
    for (int cb = 0; cb < 4; ++cb) wvv[cb] = wv[a0 + wn * 64 + cb * 16 + lr];

#pragma unroll
    for (int rb = 0; rb < 4; ++rb) {
#pragma unroll
        for (int i = 0; i < 4; ++i) {
            int row_local = wm * 64 + rb * 16 + gk * 4 + i;   // C/D: row=(lane>>4)*4+reg
            int m = m0 + row_local;
            int n = m / TI;
            const float* dbp = db + (size_t)n * AD + a0 + wn * 64;
            float rs = 0.f;
#pragma unroll
            for (int cb = 0; cb < 4; ++cb) {
                float s = acc[rb][cb][i] + dbp[cb * 16 + lr];  // col = lane&15
                rs += fast_tanh(s) * wvv[cb];
            }
            rs += __shfl_xor(rs, 1);
            rs += __shfl_xor(rs, 2);
            rs += __shfl_xor(rs, 4);
            rs += __shfl_xor(rs, 8);
            if (lr == 0) e_red[wn * 128 + row_local] = rs;
        }
    }
    __syncthreads();
    if (tid < 128)
        e_part[(size_t)at2 * M_TOT + m0 + tid] =
            e_red[tid] + e_red[128 + tid] + e_red[256 + tid] + e_red[384 + tid];
}

// ---------------- fallback fp32 GEMM (convert-in-kernel) if ws too small ----------------
__launch_bounds__(256, 2)
__global__ void k_score_fb(const float* __restrict__ X, const float* __restrict__ W,
                           const float* __restrict__ db, const float* __restrict__ wv,
                           float* __restrict__ e_part) {
    __shared__ alignas(16) _Float16 Xs[128][72];
    __shared__ alignas(16) _Float16 Ws[128][72];
    __shared__ float e_red[2][128];

    const int tid = threadIdx.x, lane = tid & 63, wid = tid >> 6;
    const int wr = wid >> 1, wc = wid & 1;
    const int m0 = blockIdx.x * 128, a0 = blockIdx.y * 128;

    f32x4 acc[4][4];
#pragma unroll
    for (int rb = 0; rb < 4; ++rb)
#pragma unroll
        for (int cb = 0; cb < 4; ++cb) acc[rb][cb] = (f32x4){0.f, 0.f, 0.f, 0.f};

    const int lr = lane & 15;
    const int lk = (lane >> 4) << 3;

    for (int kt = 0; kt < ED; kt += 64) {
#pragma unroll
        for (int i = 0; i < 4; ++i) {
            int idx = tid + i * 256, r = idx >> 3, c = (idx & 7) << 3;
            const float* gx = X + (size_t)(m0 + r) * ED + kt + c;
            float4 x0 = *(const float4*)gx, x1 = *(const float4*)(gx + 4);
            *(f16x8*)&Xs[r][c] = cvt8(x0, x1);
            const float* gw = W + (size_t)(a0 + r) * ED + kt + c;
            float4 w0 = *(const float4*)gw, w1 = *(const float4*)(gw + 4);
            *(f16x8*)&Ws[r][c] = cvt8(w0, w1);
        }
        __syncthreads();
#pragma unroll
        for (int kb = 0; kb < 64; kb += 32) {
            f16x8 aF[4], bF[4];
#pragma unroll
            for (int rb = 0; rb < 4; ++rb) aF[rb] = *(const f16x8*)&Xs[wr * 64 + rb * 16 + lr][kb + lk];
#pragma unroll
            for (int cb = 0; cb < 4; ++cb) bF[cb] = *(const f16x8*)&Ws[wc * 64 + cb * 16 + lr][kb + lk];
#pragma unroll
            for (int rb = 0; rb < 4; ++rb)
#pragma unroll
                for (int cb = 0; cb < 4; ++cb)
                    acc[rb][cb] = __builtin_amdgcn_mfma_f32_16x16x32_f16(aF[rb], bF[cb], acc[rb][cb], 0, 0, 0);
        }
        __syncthreads();
    }

    const int lg = lane >> 4;
    float wvv[4];
#pragma unroll
    for (int cb = 0; cb < 4; ++cb) wvv[cb] = wv[a0 + wc * 64 + cb * 16 + lr];
#pragma unroll
    for (int rb = 0; rb < 4; ++rb) {
#pragma unroll
        for (int i = 0; i < 4; ++i) {
            int row_local = wr * 64 + rb * 16 + lg * 4 + i;
            int m = m0 + row_local;
            int n = m / TI;
            const float* dbp = db + (size_t)n * AD + a0 + wc * 64;
            float rs = 0.f;
#pragma unroll
            for (int cb = 0; cb < 4; ++cb) {
                float s = acc[rb][cb][i] + dbp[cb * 16 + lr];
                rs += fast_tanh(s) * wvv[cb];
            }
            rs += __shfl_xor(rs, 1);
            rs += __shfl_xor(rs, 2);
            rs += __shfl_xor(rs, 4);
            rs += __shfl_xor(rs, 8);
            if (lr == 0) e_red[wc][row_local] = rs;
        }
    }
    __syncthreads();
    if (tid < 128)
        e_part[(size_t)blockIdx.y * M_TOT + m0 + tid] = e_red[0][tid] + e_red[1][tid];
}

// ---------------- Kernel 3: masked softmax over t, per n ----------------
__global__ void k_softmax(const float* __restrict__ e_part,
                          const int* __restrict__ enc_len,
                          float* __restrict__ ali, int nparts) {
    int n = blockIdx.x;
    int len = enc_len[n];
    __shared__ float se[TI];
    __shared__ float redm[4];
    __shared__ float reds[4];
    int tid = threadIdx.x;
    int lane = tid & 63, wid = tid >> 6;

    for (int t = tid; t < TI; t += 256) {
        float s = 0.f;
        for (int p = 0; p < nparts; ++p) s += e_part[(size_t)p * M_TOT + n * TI + t];
        se[t] = s;
    }
    __syncthreads();

    float mx = -1e30f;
    for (int t = tid; t < len; t += 256) mx = fmaxf(mx, se[t]);
#pragma unroll
    for (int o = 32; o >= 1; o >>= 1) mx = fmaxf(mx, __shfl_xor(mx, o));
    if (lane == 0) redm[wid] = mx;
    __syncthreads();
    mx = fmaxf(fmaxf(redm[0], redm[1]), fmaxf(redm[2], redm[3]));

    float sm = 0.f;
    for (int t = tid; t < len; t += 256) {
        float ex = __expf(se[t] - mx);
        se[t] = ex;
        sm += ex;
    }
#pragma unroll
    for (int o = 32; o >= 1; o >>= 1) sm += __shfl_xor(sm, o);
    if (lane == 0) reds[wid] = sm;
    __syncthreads();
    float inv = 1.f / (reds[0] + reds[1] + reds[2] + reds[3]);

    for (int t = tid; t < TI; t += 256)
        ali[n * TI + t] = (t < len) ? se[t] * inv : 0.f;
}

// ---------------- Kernel 4: ctx partials over t-chunks (fp32 enc, L3-warm) ----------------
__global__ void k_ctxpart(const float* __restrict__ enc,
                          const float* __restrict__ ali,
                          float* __restrict__ cpart) {
    int s = blockIdx.x;   // 0..NSPLIT-1
    int n = blockIdx.y;   // 0..31
    int d0 = threadIdx.x * 2;
    const float* base = enc + ((size_t)n * TI + s * TCHUNK) * ED + d0;
    const float* ap = ali + n * TI + s * TCHUNK;
    float ax = 0.f, ay = 0.f;
#pragma unroll 4
    for (int t = 0; t < TCHUNK; ++t) {
        float a = ap[t];
        float2 v = *(const float2*)(base + (size_t)t * ED);
        ax = fmaf(a, v.x, ax);
        ay = fmaf(a, v.y, ay);
    }
    float2 r; r.x = ax; r.y = ay;
    *(float2*)&cpart[((size_t)(n * NSPLIT + s)) * ED + d0] = r;
}

// ---------------- Kernel 5: reduce ctx partials ----------------
__global__ void k_ctxred(const float* __restrict__ cpart, float* __restrict__ ctx) {
    int n = blockIdx.x;
    for (int d = threadIdx.x; d < ED; d += 256) {
        float sum = 0.f;
#pragma unroll
        for (int s = 0; s < NSPLIT; ++s) sum += cpart[((size_t)(n * NSPLIT + s)) * ED + d];
        ctx[(size_t)n * ED + d] = sum;
    }
}

extern "C" void kernel_launch(void* const* d_in, const int* in_sizes, int n_in,
                              void* d_out, int out_size, void* d_ws, size_t ws_size,
                              hipStream_t stream) {
    const float* enc_pad  = (const float*)d_in[0];
    const int*   enc_len  = (const int*)d_in[1];
    const float* dec_prev = (const float*)d_in[2];
    // d_in[3] = ali_prev (unused by reference)
    const float* W_enc    = (const float*)d_in[4];
    const float* b_enc    = (const float*)d_in[5];
    const float* W_dec    = (const float*)d_in[6];
    const float* w_v      = (const float*)d_in[7];

    float* out = (float*)d_out;
    float* ali = out;              // 64000 floats
    float* ctx = out + M_TOT;      // 16384 floats

    float* ws     = (float*)d_ws;
    float* db     = ws;                          // 32*512
    float* e_part = ws + NB * AD;                // up to 4*64000 (main path uses 2)
    float* cpart  = e_part + 4 * M_TOT;          // 32*20*512
    size_t fp_floats = (size_t)NB * AD + 4 * M_TOT + (size_t)NB * NSPLIT * ED;  // 600064
    _Float16* W16 = (_Float16*)((char*)d_ws + fp_floats * 4);
    size_t need = fp_floats * 4 + (size_t)512 * 1024;   // ~2.9 MB
    bool big = ws_size >= need;

    if (big) {
        hipLaunchKernelGGL(k_wconvert, dim3(160), dim3(256), 0, stream,
                           W_enc, W16, dec_prev, W_dec, b_enc, db);
        hipLaunchKernelGGL(k_score256, dim3(1008), dim3(512), 0, stream,
                           enc_pad, W16, db, w_v, e_part);
        hipLaunchKernelGGL(k_softmax, dim3(NB), dim3(256), 0, stream, e_part, enc_len, ali, 2);
    } else {
        hipLaunchKernelGGL(k_decdb, dim3(NB), dim3(256), 0, stream, dec_prev, W_dec, b_enc, db);
        hipLaunchKernelGGL(k_score_fb, dim3(M_TOT / 128, 4), dim3(256), 0, stream,
                           enc_pad, W_enc, db, w_v, e_part);
        hipLaunchKernelGGL(k_softmax, dim3(NB), dim3(256), 0, stream, e_part, enc_len, ali, 4);
    }
    hipLaunchKernelGGL(k_ctxpart, dim3(NSPLIT, NB), dim3(256), 0, stream, enc_pad, ali, cpart);
    hipLaunchKernelGGL(k_ctxred, dim3(NB), dim3(256), 0, stream, cpart, ctx);
}

// Round 16
// 132.124 us; speedup vs baseline: 1.2522x; 1.0026x over previous
//
#include <hip/hip_runtime.h>
#include <stdint.h>

// CtxAttention: additive attention (Bahdanau).
//   e[n,t]  = sum_a w_v[a] * tanh( enc_pad[n,t,:]·W_enc[a,:] + b_enc[a] + dec_prev[n,:]·W_dec[a,:] )
//   ali     = softmax_t(mask(e));  ctx[n,:] = sum_t ali[n,t] * enc_pad[n,t,:]
// Round-15: test CROSS-BLOCK overlap. Every fused score so far ran 1 block/CU
// (LDS>=96KB) -> all waves share one barrier -> CU idles at every vmcnt drain
// (R13: more waves in ONE block = null). Now BM=128 x BN=256, BK=32 dbuf,
// LDS=64KB -> 2 independent blocks/CU can slip past each other's barriers (m114).
// A: R13's verified fp32 GLD16 (XOR-src) + cvt-on-read. B: per-at2 k-major panels,
// conflict-free. Grid 1000, at2-pairs XCD-grouped. R14's contiguity theory dead
// (m97 ran same strided pattern fast; R14 also self-inflicted 1KB-stride conflicts).

#define NB  32
#define TI  2000
#define ED  512
#define AD  512
#define M_TOT (NB * TI)          // 64000
#define NSPLIT 20
#define TCHUNK (TI / NSPLIT)     // 100
#define MTS 500                  // 128-row m-tiles
#define NKS 16                   // K-steps of 32

using f16x8 = __attribute__((ext_vector_type(8))) _Float16;
using f32x4 = __attribute__((ext_vector_type(4))) float;

#define GLD16(g, l)                                                     \
    __builtin_amdgcn_global_load_lds(                                   \
        (const __attribute__((address_space(1))) void*)(g),             \
        (__attribute__((address_space(3))) void*)(l), 16, 0, 0)

__device__ __forceinline__ float fast_tanh(float s) {
    s = fminf(fmaxf(s, -15.f), 15.f);
    float t = __expf(2.f * s);
    return __fdividef(t - 1.f, t + 1.f);
}

__device__ __forceinline__ f16x8 cvt8(float4 a, float4 b) {
    f16x8 h;
    h[0] = (_Float16)a.x; h[1] = (_Float16)a.y; h[2] = (_Float16)a.z; h[3] = (_Float16)a.w;
    h[4] = (_Float16)b.x; h[5] = (_Float16)b.y; h[6] = (_Float16)b.z; h[7] = (_Float16)b.w;
    return h;
}

// ---------------- Kernel 0: W_enc -> W16 (512 KB, k-major panels); + fused decdb ----------
// W16: 16 slabs (ks) of 32 KB; slab = 4 panels (gk) of 8 KB; panel: a (0..511) x 16 B
// holding f16 W_enc[a][ks*32+gk*8 .. +8].
// bx in [0,128): convert; [128,160): decdb row n = bx-128.
__global__ void k_wconvert(const float* __restrict__ Wenc, _Float16* __restrict__ W16,
                           const float* __restrict__ dec_prev, const float* __restrict__ W_dec,
                           const float* __restrict__ b_enc, float* __restrict__ db) {
    __shared__ float xd[ED];
    int bx = blockIdx.x;
    int tid = threadIdx.x;
    if (bx >= 128) {
        int n = bx - 128;
        for (int k = tid; k < ED; k += 256) xd[k] = dec_prev[n * ED + k];
        __syncthreads();
        for (int a = tid; a < AD; a += 256) {
            const float* wr = W_dec + (size_t)a * ED;
            float s = 0.f;
#pragma unroll 8
            for (int k = 0; k < ED; k += 4) {
                float4 w = *(const float4*)(wr + k);
                s += xd[k] * w.x + xd[k + 1] * w.y + xd[k + 2] * w.z + xd[k + 3] * w.w;
            }
            db[n * AD + a] = s + b_enc[a];
        }
        return;
    }
    int idx = bx * 4096 + tid * 16;    // physical byte in W16 (512 KB)
    int ks  = idx >> 15;               // slab 0..15
    int r   = idx & 32767;
    int gk  = r >> 13;                 // panel 0..3
    int a   = (r & 8191) >> 4;         // row 0..511
    int k   = ks * 32 + gk * 8;
    const float* s = Wenc + (size_t)a * ED + k;
    float4 x0 = *(const float4*)s;
    float4 x1 = *(const float4*)(s + 4);
    *(f16x8*)((char*)W16 + idx) = cvt8(x0, x1);
}

// ---------------- standalone decdb (fallback path only) ----------------
__global__ void k_decdb(const float* __restrict__ dec_prev,
                        const float* __restrict__ W_dec,
                        const float* __restrict__ b_enc,
                        float* __restrict__ db) {
    int n = blockIdx.x;
    __shared__ float xd[ED];
    for (int k = threadIdx.x; k < ED; k += 256) xd[k] = dec_prev[n * ED + k];
    __syncthreads();
    for (int a = threadIdx.x; a < AD; a += 256) {
        const float* wr = W_dec + (size_t)a * ED;
        float s = 0.f;
#pragma unroll 8
        for (int k = 0; k < ED; k += 4) {
            float4 w = *(const float4*)(wr + k);
            s += xd[k] * w.x + xd[k + 1] * w.y + xd[k + 2] * w.z + xd[k + 3] * w.w;
        }
        db[n * AD + a] = s + b_enc[a];
    }
}

// ---------------- Kernel 2: fused score GEMM, 128x256 tile, 8 waves, 64KB LDS ----------
// grid 1008: fid -> g=fid>>4, r=fid&15, at2=r>>3, mt=g*8+(r&7) -> the two at2 blocks
// of one mt are 8 apart in fid (same XCD under round-robin) for enc L2 reuse.
__launch_bounds__(512, 2)
__global__ void k_score256(const float* __restrict__ enc, const _Float16* __restrict__ W16,
                           const float* __restrict__ db, const float* __restrict__ wv,
                           float* __restrict__ e_part) {
    __shared__ alignas(16) char As0[16384];   // 128 x 32 fp32, 128B rows, XOR-swizzled
    __shared__ alignas(16) char As1[16384];
    __shared__ alignas(16) char Bs0[16384];   // 4 k-panels x (256 x 16B f16), linear
    __shared__ alignas(16) char Bs1[16384];

    int fid = blockIdx.x;
    int g = fid >> 4, r = fid & 15;
    int at2 = r >> 3;
    int mt  = g * 8 + (r & 7);
    if (mt >= MTS) return;

    const int tid  = threadIdx.x;
    const int lane = tid & 63;
    const int w    = tid >> 6;        // wave 0..7
    const int wm   = w >> 2;          // M-half: rows wm*64..+64
    const int wn   = w & 3;           // N-quarter: cols wn*64..+64
    const int m0   = mt * 128;
    const int a0   = at2 * 256;
    const int lr   = lane & 15;
    const int gk   = lane >> 4;       // k-group 0..3

    // A staging: 2 GLD16/thread. LDS bytes d and d+8192; row(d)=d>>7 (0..127),
    // within-row swizzled source (inverse of read-side XOR). row(d+8192)=row(d)+64
    // has the same (row&7) -> same swizzle offset.
    const int da   = tid * 16;                          // 0..8176
    const int arow = da >> 7;                           // 0..63
    const int aswz = ((da & 127) ^ ((arow & 7) << 4)) >> 2;
    const float* asrc = enc + (size_t)(m0 + arow) * ED + aswz;

    // B staging: 2 GLD16/thread. Dest byte d: gk=d>>12, r16=(d&4095)>>4 (0..255);
    // src = W16 + (ks<<15) + gk*8192 + at2*4096 + (d&4095).
    const char* wbase = (const char*)W16;
    const int db0 = tid * 16;           // dest 0..8176 (gk 0..1)
    const int db1 = db0 + 8192;         // dest (gk 2..3)
    const int bs0 = ((db0 >> 12) << 13) + at2 * 4096 + (db0 & 4095);
    const int bs1 = ((db1 >> 12) << 13) + at2 * 4096 + (db1 & 4095);

    f32x4 acc[4][4];
#pragma unroll
    for (int rb = 0; rb < 4; ++rb)
#pragma unroll
        for (int cb = 0; cb < 4; ++cb) acc[rb][cb] = (f32x4){0.f, 0.f, 0.f, 0.f};

#define STAGE(ks, dA, dB)                                               \
    {                                                                   \
        GLD16(asrc + (ks) * 32,            (dA) + da);                  \
        GLD16(asrc + 64 * ED + (ks) * 32,  (dA) + da + 8192);           \
        const char* wsl = wbase + ((ks) << 15);                         \
        GLD16(wsl + bs0, (dB) + db0);                                   \
        GLD16(wsl + bs1, (dB) + db1);                                   \
    }

#define COMPUTE(sA, sB)                                                          \
    {                                                                            \
        f16x8 aF[4], bF[4];                                                      \
        _Pragma("unroll")                                                        \
        for (int rb = 0; rb < 4; ++rb) {                                         \
            int row = wm * 64 + rb * 16 + lr;                                    \
            int b0  = row * 128 + gk * 32;                                       \
            int sw  = (row & 7) << 4;                                            \
            f32x4 lo = *(const f32x4*)((sA) + (b0 ^ sw));                        \
            f32x4 hi = *(const f32x4*)((sA) + ((b0 + 16) ^ sw));                 \
            f16x8 h;                                                             \
            h[0] = (_Float16)lo[0]; h[1] = (_Float16)lo[1];                      \
            h[2] = (_Float16)lo[2]; h[3] = (_Float16)lo[3];                      \
            h[4] = (_Float16)hi[0]; h[5] = (_Float16)hi[1];                      \
            h[6] = (_Float16)hi[2]; h[7] = (_Float16)hi[3];                      \
            aF[rb] = h;                                                          \
        }                                                                        \
        _Pragma("unroll")                                                        \
        for (int cb = 0; cb < 4; ++cb) {                                         \
            int brow = wn * 64 + cb * 16 + lr;                                   \
            bF[cb] = *(const f16x8*)((sB) + gk * 4096 + brow * 16);              \
        }                                                                        \
        __builtin_amdgcn_s_setprio(1);                                           \
        _Pragma("unroll")                                                        \
        for (int rb = 0; rb < 4; ++rb)                                           \
            _Pragma("unroll")                                                    \
            for (int cb = 0; cb < 4; ++cb)                                       \
                acc[rb][cb] = __builtin_amdgcn_mfma_f32_16x16x32_f16(            \
                    aF[rb], bF[cb], acc[rb][cb], 0, 0, 0);                       \
        __builtin_amdgcn_s_setprio(0);                                           \
    }

#define ITER(k, Ac, Bc, An, Bn)  STAGE(k + 1, An, Bn); COMPUTE(Ac, Bc); __syncthreads();

    STAGE(0, As0, Bs0); __syncthreads();
    ITER(0,  As0, Bs0, As1, Bs1)
    ITER(1,  As1, Bs1, As0, Bs0)
    ITER(2,  As0, Bs0, As1, Bs1)
    ITER(3,  As1, Bs1, As0, Bs0)
    ITER(4,  As0, Bs0, As1, Bs1)
    ITER(5,  As1, Bs1, As0, Bs0)
    ITER(6,  As0, Bs0, As1, Bs1)
    ITER(7,  As1, Bs1, As0, Bs0)
    ITER(8,  As0, Bs0, As1, Bs1)
    ITER(9,  As1, Bs1, As0, Bs0)
    ITER(10, As0, Bs0, As1, Bs1)
    ITER(11, As1, Bs1, As0, Bs0)
    ITER(12, As0, Bs0, As1, Bs1)
    ITER(13, As1, Bs1, As0, Bs0)
    ITER(14, As0, Bs0, As1, Bs1)
    COMPUTE(As1, Bs1); __syncthreads();
#undef ITER
#undef COMPUTE
#undef STAGE

    // epilogue: rs = sum over this wave's 64 cols of w_v*tanh(acc+db); shfl-reduce the
    // 16 col-lanes; cross-wave (4 wn quarters) reduce via e_red overlaid on As0.
    float* e_red = (float*)As0;   // [4][128] = 2 KB
    float wvv[4];
#pragma unroll
    for (int cb = 0; cb < 4; ++cb) wvv[cb] = wv[a0 + wn * 64 + cb * 16 + lr];

#pragma unroll
    for (int rb = 0; rb < 4; ++rb) {
#pragma unroll
        for (int i = 0; i < 4; ++i) {
            int row_local = wm * 64 + rb * 16 + gk * 4 + i;   // C/D: row=(lane>>4)*4+reg
            int m = m0 + row_local;
            int n = m / TI;
            const float* dbp = db + (size_t)n * AD + a0 + wn * 64;
            float rs = 0.f;
#pragma unroll
            for (int cb = 0; cb < 4; ++cb) {
                float s = acc[rb][cb][i] + dbp[cb * 16 + lr];  // col = lane&15
                rs += fast_tanh(s) * wvv[cb];
            }
            rs += __shfl_xor(rs, 1);
            rs += __shfl_xor(rs, 2);
            rs += __shfl_xor(rs, 4);
            rs += __shfl_xor(rs, 8);
            if (lr == 0) e_red[wn * 128 + row_local] = rs;
        }
    }
    __syncthreads();
    if (tid < 128)
        e_part[(size_t)at2 * M_TOT + m0 + tid] =
            e_red[tid] + e_red[128 + tid] + e_red[256 + tid] + e_red[384 + tid];
}

// ---------------- fallback fp32 GEMM (convert-in-kernel) if ws too small ----------------
__launch_bounds__(256, 2)
__global__ void k_score_fb(const float* __restrict__ X, const float* __restrict__ W,
                           const float* __restrict__ db, const float* __restrict__ wv,
                           float* __restrict__ e_part) {
    __shared__ alignas(16) _Float16 Xs[128][72];
    __shared__ alignas(16) _Float16 Ws[128][72];
    __shared__ float e_red[2][128];

    const int tid = threadIdx.x, lane = tid & 63, wid = tid >> 6;
    const int wr = wid >> 1, wc = wid & 1;
    const int m0 = blockIdx.x * 128, a0 = blockIdx.y * 128;

    f32x4 acc[4][4];
#pragma unroll
    for (int rb = 0; rb < 4; ++rb)
#pragma unroll
        for (int cb = 0; cb < 4; ++cb) acc[rb][cb] = (f32x4){0.f, 0.f, 0.f, 0.f};

    const int lr = lane & 15;
    const int lk = (lane >> 4) << 3;

    for (int kt = 0; kt < ED; kt += 64) {
#pragma unroll
        for (int i = 0; i < 4; ++i) {
            int idx = tid + i * 256, r = idx >> 3, c = (idx & 7) << 3;
            const float* gx = X + (size_t)(m0 + r) * ED + kt + c;
            float4 x0 = *(const float4*)gx, x1 = *(const float4*)(gx + 4);
            *(f16x8*)&Xs[r][c] = cvt8(x0, x1);
            const float* gw = W + (size_t)(a0 + r) * ED + kt + c;
            float4 w0 = *(const float4*)gw, w1 = *(const float4*)(gw + 4);
            *(f16x8*)&Ws[r][c] = cvt8(w0, w1);
        }
        __syncthreads();
#pragma unroll
        for (int kb = 0; kb < 64; kb += 32) {
            f16x8 aF[4], bF[4];
#pragma unroll
            for (int rb = 0; rb < 4; ++rb) aF[rb] = *(const f16x8*)&Xs[wr * 64 + rb * 16 + lr][kb + lk];
#pragma unroll
            for (int cb = 0; cb < 4; ++cb) bF[cb] = *(const f16x8*)&Ws[wc * 64 + cb * 16 + lr][kb + lk];
#pragma unroll
            for (int rb = 0; rb < 4; ++rb)
#pragma unroll
                for (int cb = 0; cb < 4; ++cb)
                    acc[rb][cb] = __builtin_amdgcn_mfma_f32_16x16x32_f16(aF[rb], bF[cb], acc[rb][cb], 0, 0, 0);
        }
        __syncthreads();
    }

    const int lg = lane >> 4;
    float wvv[4];
#pragma unroll
    for (int cb = 0; cb < 4; ++cb) wvv[cb] = wv[a0 + wc * 64 + cb * 16 + lr];
#pragma unroll
    for (int rb = 0; rb < 4; ++rb) {
#pragma unroll
        for (int i = 0; i < 4; ++i) {
            int row_local = wr * 64 + rb * 16 + lg * 4 + i;
            int m = m0 + row_local;
            int n = m / TI;
            const float* dbp = db + (size_t)n * AD + a0 + wc * 64;
            float rs = 0.f;
#pragma unroll
            for (int cb = 0; cb < 4; ++cb) {
                float s = acc[rb][cb][i] + dbp[cb * 16 + lr];
                rs += fast_tanh(s) * wvv[cb];
            }
            rs += __shfl_xor(rs, 1);
            rs += __shfl_xor(rs, 2);
            rs += __shfl_xor(rs, 4);
            rs += __shfl_xor(rs, 8);
            if (lr == 0) e_red[wc][row_local] = rs;
        }
    }
    __syncthreads();
    if (tid < 128)
        e_part[(size_t)blockIdx.y * M_TOT + m0 + tid] = e_red[0][tid] + e_red[1][tid];
}

// ---------------- Kernel 3: masked softmax over t, per n ----------------
__global__ void k_softmax(const float* __restrict__ e_part,
                          const int* __restrict__ enc_len,
                          float* __restrict__ ali, int nparts) {
    int n = blockIdx.x;
    int len = enc_len[n];
    __shared__ float se[TI];
    __shared__ float redm[4];
    __shared__ float reds[4];
    int tid = threadIdx.x;
    int lane = tid & 63, wid = tid >> 6;

    for (int t = tid; t < TI; t += 256) {
        float s = 0.f;
        for (int p = 0; p < nparts; ++p) s += e_part[(size_t)p * M_TOT + n * TI + t];
        se[t] = s;
    }
    __syncthreads();

    float mx = -1e30f;
    for (int t = tid; t < len; t += 256) mx = fmaxf(mx, se[t]);
#pragma unroll
    for (int o = 32; o >= 1; o >>= 1) mx = fmaxf(mx, __shfl_xor(mx, o));
    if (lane == 0) redm[wid] = mx;
    __syncthreads();
    mx = fmaxf(fmaxf(redm[0], redm[1]), fmaxf(redm[2], redm[3]));

    float sm = 0.f;
    for (int t = tid; t < len; t += 256) {
        float ex = __expf(se[t] - mx);
        se[t] = ex;
        sm += ex;
    }
#pragma unroll
    for (int o = 32; o >= 1; o >>= 1) sm += __shfl_xor(sm, o);
    if (lane == 0) reds[wid] = sm;
    __syncthreads();
    float inv = 1.f / (reds[0] + reds[1] + reds[2] + reds[3]);

    for (int t = tid; t < TI; t += 256)
        ali[n * TI + t] = (t < len) ? se[t] * inv : 0.f;
}

// ---------------- Kernel 4: ctx partials over t-chunks (fp32 enc, L3-warm) ----------------
__global__ void k_ctxpart(const float* __restrict__ enc,
                          const float* __restrict__ ali,
                          float* __restrict__ cpart) {
    int s = blockIdx.x;   // 0..NSPLIT-1
    int n = blockIdx.y;   // 0..31
    int d0 = threadIdx.x * 2;
    const float* base = enc + ((size_t)n * TI + s * TCHUNK) * ED + d0;
    const float* ap = ali + n * TI + s * TCHUNK;
    float ax = 0.f, ay = 0.f;
#pragma unroll 4
    for (int t = 0; t < TCHUNK; ++t) {
        float a = ap[t];
        float2 v = *(const float2*)(base + (size_t)t * ED);
        ax = fmaf(a, v.x, ax);
        ay = fmaf(a, v.y, ay);
    }
    float2 r; r.x = ax; r.y = ay;
    *(float2*)&cpart[((size_t)(n * NSPLIT + s)) * ED + d0] = r;
}

// ---------------- Kernel 5: reduce ctx partials ----------------
__global__ void k_ctxred(const float* __restrict__ cpart, float* __restrict__ ctx) {
    int n = blockIdx.x;
    for (int d = threadIdx.x; d < ED; d += 256) {
        float sum = 0.f;
#pragma unroll
        for (int s = 0; s < NSPLIT; ++s) sum += cpart[((size_t)(n * NSPLIT + s)) * ED + d];
        ctx[(size_t)n * ED + d] = sum;
    }
}

extern "C" void kernel_launch(void* const* d_in, const int* in_sizes, int n_in,
                              void* d_out, int out_size, void* d_ws, size_t ws_size,
                              hipStream_t stream) {
    const float* enc_pad  = (const float*)d_in[0];
    const int*   enc_len  = (const int*)d_in[1];
    const float* dec_prev = (const float*)d_in[2];
    // d_in[3] = ali_prev (unused by reference)
    const float* W_enc    = (const float*)d_in[4];
    const float* b_enc    = (const float*)d_in[5];
    const float* W_dec    = (const float*)d_in[6];
    const float* w_v      = (const float*)d_in[7];

    float* out = (float*)d_out;
    float* ali = out;              // 64000 floats
    float* ctx = out + M_TOT;      // 16384 floats

    float* ws     = (float*)d_ws;
    float* db     = ws;                          // 32*512
    float* e_part = ws + NB * AD;                // up to 4*64000 (main path uses 2)
    float* cpart  = e_part + 4 * M_TOT;          // 32*20*512
    size_t fp_floats = (size_t)NB * AD + 4 * M_TOT + (size_t)NB * NSPLIT * ED;  // 600064
    _Float16* W16 = (_Float16*)((char*)d_ws + fp_floats * 4);
    size_t need = fp_floats * 4 + (size_t)512 * 1024;   // ~2.9 MB
    bool big = ws_size >= need;

    if (big) {
        hipLaunchKernelGGL(k_wconvert, dim3(160), dim3(256), 0, stream,
                           W_enc, W16, dec_prev, W_dec, b_enc, db);
        hipLaunchKernelGGL(k_score256, dim3(1008), dim3(512), 0, stream,
                           enc_pad, W16, db, w_v, e_part);
        hipLaunchKernelGGL(k_softmax, dim3(NB), dim3(256), 0, stream, e_part, enc_len, ali, 2);
    } else {
        hipLaunchKernelGGL(k_decdb, dim3(NB), dim3(256), 0, stream, dec_prev, W_dec, b_enc, db);
        hipLaunchKernelGGL(k_score_fb, dim3(M_TOT / 128, 4), dim3(256), 0, stream,
                           enc_pad, W_enc, db, w_v, e_part);
        hipLaunchKernelGGL(k_softmax, dim3(NB), dim3(256), 0, stream, e_part, enc_len, ali, 4);
    }
    hipLaunchKernelGGL(k_ctxpart, dim3(NSPLIT, NB), dim3(256), 0, stream, enc_pad, ali, cpart);
    hipLaunchKernelGGL(k_ctxred, dim3(NB), dim3(256), 0, stream, cpart, ctx);
}